// Round 1
// baseline (190.791 us; speedup 1.0000x reference)
//
#include <hip/hip_runtime.h>
#include <math.h>

#define N_NODES 2048
#define FIN 128
#define FOUT 64
#define BS 8
#define BM 32
#define BK 32
#define ALPHA 0.2f
#define NEG_BIG (-9.0e15f)

// ---------------- Kernel A: h = x @ W ; s1 = h@a1 ; s2 = h@a2 ----------------
// 256 threads = 4 waves; each wave computes one (b,n) row; lane = output index o.
__global__ __launch_bounds__(256) void gat_h(const float* __restrict__ x,
                                             const float* __restrict__ W,
                                             const float* __restrict__ a,
                                             float* __restrict__ h,
                                             float* __restrict__ s1,
                                             float* __restrict__ s2) {
  const int lane = threadIdx.x & 63;
  const int wv = threadIdx.x >> 6;
  const int row = blockIdx.x * 4 + wv;           // 0 .. BS*N_NODES-1
  const float* xr = x + (long long)row * FIN;
  float acc = 0.f;
  #pragma unroll 4
  for (int f = 0; f < FIN; f += 4) {
    const float4 xv = *reinterpret_cast<const float4*>(xr + f);
    acc = fmaf(xv.x, W[(f + 0) * FOUT + lane], acc);
    acc = fmaf(xv.y, W[(f + 1) * FOUT + lane], acc);
    acc = fmaf(xv.z, W[(f + 2) * FOUT + lane], acc);
    acc = fmaf(xv.w, W[(f + 3) * FOUT + lane], acc);
  }
  h[(long long)row * FOUT + lane] = acc;
  float r1 = acc * a[lane];
  float r2 = acc * a[FOUT + lane];
  #pragma unroll
  for (int off = 32; off > 0; off >>= 1) {
    r1 += __shfl_xor(r1, off);
    r2 += __shfl_xor(r2, off);
  }
  if (lane == 0) { s1[row] = r1; s2[row] = r2; }
}

__device__ __forceinline__ float elu_f(float v) {
  return v > 0.f ? v : expm1f(v);
}

// ------------- Kernel B: masked softmax(att) @ h, fused, per 32-row tile ------
__global__ __launch_bounds__(256) void gat_attn(const int* __restrict__ adj,
                                                const float* __restrict__ h,
                                                const float* __restrict__ s1g,
                                                const float* __restrict__ s2g,
                                                float* __restrict__ out) {
  const int b = blockIdx.y;
  const int ib = blockIdx.x * BM;
  const int t = threadIdx.x;

  __shared__ float h_s[BK][FOUT];        // 8 KB
  __shared__ float p_s[BM][BK + 1];      // 4.1 KB, +1 pad breaks bank aliasing
  __shared__ float m_s[BM], li_s[BM], s1_s[BM];

  const float* hB = h + (long long)b * N_NODES * FOUT;
  const float* s2B = s2g + b * N_NODES;

  if (t < BM) s1_s[t] = s1g[b * N_NODES + ib + t];
  __syncthreads();

  // ---- pass 1: per-row online (max, sumexp); 8 threads per row ----
  {
    const int il = t >> 3;
    const int jl = t & 7;
    const float s1v = s1_s[il];
    const int* adjRow = adj + (long long)(ib + il) * N_NODES;
    float m = -INFINITY, l = 0.f;
    for (int j = jl; j < N_NODES; j += 8) {
      float sc = s1v + s2B[j];
      sc = sc >= 0.f ? sc : ALPHA * sc;
      sc = (adjRow[j] > 0) ? sc : NEG_BIG;
      if (sc > m) { l = l * __expf(m - sc) + 1.f; m = sc; }
      else        { l += __expf(sc - m); }
    }
    #pragma unroll
    for (int off = 1; off < 8; off <<= 1) {
      const float mo = __shfl_xor(m, off);
      const float lo = __shfl_xor(l, off);
      const float mn = fmaxf(m, mo);
      l = l * __expf(m - mn) + lo * __expf(mo - mn);
      m = mn;
    }
    if (jl == 0) { m_s[il] = m; li_s[il] = 1.0f / l; }
  }

  // ---- pass 2: accumulate out[i][o] = sum_j exp(sc-m) * h[j][o] ----
  const int rg = t >> 4;    // 0..15 -> rows 2*rg, 2*rg+1
  const int cg = t & 15;    // 0..15 -> cols 4*cg .. 4*cg+3
  float acc[2][4] = {{0.f, 0.f, 0.f, 0.f}, {0.f, 0.f, 0.f, 0.f}};

  for (int j0 = 0; j0 < N_NODES; j0 += BK) {
    __syncthreads();
    // stage h tile (32 x 64 f32), coalesced float4 loads
    {
      const int jj = t >> 3;
      const int oo = (t & 7) * 8;
      const float* src = hB + (long long)(j0 + jj) * FOUT + oo;
      *reinterpret_cast<float4*>(&h_s[jj][oo])     = *reinterpret_cast<const float4*>(src);
      *reinterpret_cast<float4*>(&h_s[jj][oo + 4]) = *reinterpret_cast<const float4*>(src + 4);
    }
    // compute p tile (32 x 32), 4 per thread, coalesced adj reads
    {
      const int jl = t & 31;
      const float s2v = s2B[j0 + jl];
      #pragma unroll
      for (int q = 0; q < 4; q++) {
        const int il = (t >> 5) + q * 8;
        float sc = s1_s[il] + s2v;
        sc = sc >= 0.f ? sc : ALPHA * sc;
        sc = (adj[(long long)(ib + il) * N_NODES + j0 + jl] > 0) ? sc : NEG_BIG;
        p_s[il][jl] = __expf(sc - m_s[il]);
      }
    }
    __syncthreads();
    #pragma unroll 8
    for (int j = 0; j < BK; j++) {
      const float pa = p_s[2 * rg][j];
      const float pb = p_s[2 * rg + 1][j];
      const float4 hv = *reinterpret_cast<const float4*>(&h_s[j][4 * cg]);
      acc[0][0] = fmaf(pa, hv.x, acc[0][0]);
      acc[0][1] = fmaf(pa, hv.y, acc[0][1]);
      acc[0][2] = fmaf(pa, hv.z, acc[0][2]);
      acc[0][3] = fmaf(pa, hv.w, acc[0][3]);
      acc[1][0] = fmaf(pb, hv.x, acc[1][0]);
      acc[1][1] = fmaf(pb, hv.y, acc[1][1]);
      acc[1][2] = fmaf(pb, hv.z, acc[1][2]);
      acc[1][3] = fmaf(pb, hv.w, acc[1][3]);
    }
  }

  const float inva = li_s[2 * rg];
  const float invb = li_s[2 * rg + 1];
  float4 oa, ob;
  oa.x = elu_f(acc[0][0] * inva); oa.y = elu_f(acc[0][1] * inva);
  oa.z = elu_f(acc[0][2] * inva); oa.w = elu_f(acc[0][3] * inva);
  ob.x = elu_f(acc[1][0] * invb); ob.y = elu_f(acc[1][1] * invb);
  ob.z = elu_f(acc[1][2] * invb); ob.w = elu_f(acc[1][3] * invb);

  const long long obase = ((long long)b * N_NODES + ib + 2 * rg) * FOUT + 4 * cg;
  *reinterpret_cast<float4*>(out + obase)        = oa;
  *reinterpret_cast<float4*>(out + obase + FOUT) = ob;
}

extern "C" void kernel_launch(void* const* d_in, const int* in_sizes, int n_in,
                              void* d_out, int out_size, void* d_ws, size_t ws_size,
                              hipStream_t stream) {
  const float* x   = (const float*)d_in[0];
  const int*   adj = (const int*)d_in[1];
  const float* W   = (const float*)d_in[2];
  const float* a   = (const float*)d_in[3];
  float* out = (float*)d_out;

  float* h  = (float*)d_ws;                                   // BS*N*FOUT f32 = 4 MB
  float* s1 = h + (long long)BS * N_NODES * FOUT;             // BS*N
  float* s2 = s1 + BS * N_NODES;                              // BS*N

  gat_h<<<BS * N_NODES / 4, 256, 0, stream>>>(x, W, a, h, s1, s2);
  gat_attn<<<dim3(N_NODES / BM, BS), 256, 0, stream>>>(adj, h, s1, s2, out);
}

// Round 2
// 69.477 us; speedup vs baseline: 2.7461x; 2.7461x over previous
//
#include <hip/hip_runtime.h>
#include <math.h>

#define N_NODES 2048
#define FIN 128
#define FOUT 64
#define BS 8
#define ALPHA 0.2f

typedef __attribute__((ext_vector_type(8))) short short8v;
typedef __attribute__((ext_vector_type(4))) float f32x4;

__device__ __forceinline__ short f2bf(float f) {
  unsigned u = __float_as_uint(f);
  unsigned r = (u + 0x7FFFu + ((u >> 16) & 1u)) >> 16;   // RNE
  return (short)r;
}

// ---------------- Kernel A: h = x @ W ; s1 = h@a1 ; s2 = h@a2 ----------------
__global__ __launch_bounds__(256) void gat_h(const float* __restrict__ x,
                                             const float* __restrict__ W,
                                             const float* __restrict__ a,
                                             float* __restrict__ h,
                                             float* __restrict__ s1,
                                             float* __restrict__ s2) {
  const int lane = threadIdx.x & 63;
  const int wv = threadIdx.x >> 6;
  const int row = blockIdx.x * 4 + wv;           // 0 .. BS*N_NODES-1
  const float* xr = x + (long long)row * FIN;
  float acc = 0.f;
  #pragma unroll 4
  for (int f = 0; f < FIN; f += 4) {
    const float4 xv = *reinterpret_cast<const float4*>(xr + f);
    acc = fmaf(xv.x, W[(f + 0) * FOUT + lane], acc);
    acc = fmaf(xv.y, W[(f + 1) * FOUT + lane], acc);
    acc = fmaf(xv.z, W[(f + 2) * FOUT + lane], acc);
    acc = fmaf(xv.w, W[(f + 3) * FOUT + lane], acc);
  }
  h[(long long)row * FOUT + lane] = acc;
  float r1 = acc * a[lane];
  float r2 = acc * a[FOUT + lane];
  #pragma unroll
  for (int off = 32; off > 0; off >>= 1) {
    r1 += __shfl_xor(r1, off);
    r2 += __shfl_xor(r2, off);
  }
  if (lane == 0) { s1[row] = r1; s2[row] = r2; }
}

// ------------- pack_h: h fp32 row-major -> bf16 B-fragment layout -------------
// One wave per 32x16 (j x o) tile. Element (j, o) -> slot lane=((j>>3)&3)*16+(o&15),
// e=j&7 of tile (b, jt=j>>5, ct=o>>4). Lane writes its 8 elems as one 16B store.
__global__ __launch_bounds__(256) void pack_h(const float* __restrict__ h,
                                              short* __restrict__ hp) {
  const int g = (blockIdx.x * 256 + threadIdx.x) >> 6;   // 0..2047
  const int lane = threadIdx.x & 63;
  const int b = g >> 8, rem = g & 255, jt = rem >> 2, ct = rem & 3;
  const int kg = lane >> 4, cl = lane & 15;
  const float* src = h + ((long long)b * N_NODES + jt * 32 + kg * 8) * FOUT + ct * 16 + cl;
  short8v o;
  #pragma unroll
  for (int e = 0; e < 8; e++) o[e] = f2bf(src[e * FOUT]);
  *reinterpret_cast<short8v*>(hp + ((long long)g * 64 + lane) * 8) = o;
}

// ------------- pack_mask: adj int32 -> bitmask (uint32 per 32 j's) ------------
__global__ __launch_bounds__(256) void pack_mask(const int* __restrict__ adj,
                                                 unsigned int* __restrict__ mask32) {
  const int wid = (blockIdx.x * 256 + threadIdx.x) >> 6;  // 0..65535
  const int lane = threadIdx.x & 63;
  const int row = wid >> 5;                // 32 waves per row
  const int jb = (wid & 31) << 6;          // 64 j's per wave
  const int v = adj[(long long)row * N_NODES + jb + lane];
  const unsigned long long bal = __ballot(v > 0);
  if (lane == 0) mask32[row * 64 + (jb >> 5)] = (unsigned int)bal;
  if (lane == 1) mask32[row * 64 + (jb >> 5) + 1] = (unsigned int)(bal >> 32);
}

__device__ __forceinline__ float elu_f(float v) {
  return v > 0.f ? v : expm1f(v);
}

// ------------- Kernel B: fused p-gen (regs) + MFMA PV, no main-loop barriers --
// Block: 4 waves, 16 rows (i0..i0+15). Wave w handles j-tiles w, w+4, ...
// A-frag: lane l holds p[row=l&15][k=(l>>4)*8+e]. C/D: col=l&15, row=(l>>4)*4+r.
__global__ __launch_bounds__(256) void gat_attn(const unsigned int* __restrict__ mask32,
                                                const short* __restrict__ hp,
                                                const float* __restrict__ s1g,
                                                const float* __restrict__ s2g,
                                                float* __restrict__ out) {
  const int b = blockIdx.y;
  const int i0 = blockIdx.x * 16;
  const int w = threadIdx.x >> 6;
  const int lane = threadIdx.x & 63;
  const int kg = lane >> 4, rl = lane & 15;

  __shared__ float red[4][16 * 64];   // 16 KB
  __shared__ float ps[4][16];

  const float s1v = s1g[b * N_NODES + i0 + rl];
  const float* s2B = s2g + b * N_NODES;
  const unsigned int* mrow = mask32 + (i0 + rl) * 64;
  const short8v* hpB = reinterpret_cast<const short8v*>(hp) + (long long)b * 64 * 4 * 64;

  f32x4 acc0 = {0.f, 0.f, 0.f, 0.f};
  f32x4 acc1 = {0.f, 0.f, 0.f, 0.f};
  f32x4 acc2 = {0.f, 0.f, 0.f, 0.f};
  f32x4 acc3 = {0.f, 0.f, 0.f, 0.f};
  float psum = 0.f;

  for (int jt = w; jt < 64; jt += 4) {
    const int j0 = jt * 32;
    const int jb = j0 + kg * 8;
    const float4 sa = *reinterpret_cast<const float4*>(s2B + jb);
    const float4 sb = *reinterpret_cast<const float4*>(s2B + jb + 4);
    const unsigned int m = mrow[j0 >> 5] >> (kg * 8);
    const float s2e[8] = {sa.x, sa.y, sa.z, sa.w, sb.x, sb.y, sb.z, sb.w};
    short8v af;
    #pragma unroll
    for (int e = 0; e < 8; e++) {
      float sc = s1v + s2e[e];
      sc = fmaxf(sc, ALPHA * sc);                 // leaky-relu (alpha < 1)
      float pe = ((m >> e) & 1u) ? __expf(sc) : 0.f;
      psum += pe;
      af[e] = f2bf(pe);
    }
    const short8v* hpt = hpB + (long long)jt * 4 * 64;
    const short8v b0 = hpt[0 * 64 + lane];
    const short8v b1 = hpt[1 * 64 + lane];
    const short8v b2 = hpt[2 * 64 + lane];
    const short8v b3 = hpt[3 * 64 + lane];
    acc0 = __builtin_amdgcn_mfma_f32_16x16x32_bf16(af, b0, acc0, 0, 0, 0);
    acc1 = __builtin_amdgcn_mfma_f32_16x16x32_bf16(af, b1, acc1, 0, 0, 0);
    acc2 = __builtin_amdgcn_mfma_f32_16x16x32_bf16(af, b2, acc2, 0, 0, 0);
    acc3 = __builtin_amdgcn_mfma_f32_16x16x32_bf16(af, b3, acc3, 0, 0, 0);
  }

  // row-sum: lanes l, l^16, l^32, l^48 share row rl
  psum += __shfl_xor(psum, 16);
  psum += __shfl_xor(psum, 32);
  if (lane < 16) ps[w][lane] = psum;

  #pragma unroll
  for (int r = 0; r < 4; r++) {
    red[w][(kg * 4 + r) * 64 + 0 * 16 + rl] = acc0[r];
    red[w][(kg * 4 + r) * 64 + 1 * 16 + rl] = acc1[r];
    red[w][(kg * 4 + r) * 64 + 2 * 16 + rl] = acc2[r];
    red[w][(kg * 4 + r) * 64 + 3 * 16 + rl] = acc3[r];
  }
  __syncthreads();

  // epilogue: 256 threads, 4 outputs each
  const int row = threadIdx.x >> 4;
  const int col = (threadIdx.x & 15) * 4;
  const float den = ps[0][row] + ps[1][row] + ps[2][row] + ps[3][row];
  const float inv = 1.0f / den;
  float4 ov;
  {
    const int base = row * 64 + col;
    float v0 = red[0][base + 0] + red[1][base + 0] + red[2][base + 0] + red[3][base + 0];
    float v1 = red[0][base + 1] + red[1][base + 1] + red[2][base + 1] + red[3][base + 1];
    float v2 = red[0][base + 2] + red[1][base + 2] + red[2][base + 2] + red[3][base + 2];
    float v3 = red[0][base + 3] + red[1][base + 3] + red[2][base + 3] + red[3][base + 3];
    ov.x = elu_f(v0 * inv); ov.y = elu_f(v1 * inv);
    ov.z = elu_f(v2 * inv); ov.w = elu_f(v3 * inv);
  }
  *reinterpret_cast<float4*>(out + ((long long)b * N_NODES + i0 + row) * FOUT + col) = ov;
}

extern "C" void kernel_launch(void* const* d_in, const int* in_sizes, int n_in,
                              void* d_out, int out_size, void* d_ws, size_t ws_size,
                              hipStream_t stream) {
  const float* x   = (const float*)d_in[0];
  const int*   adj = (const int*)d_in[1];
  const float* W   = (const float*)d_in[2];
  const float* a   = (const float*)d_in[3];
  float* out = (float*)d_out;

  float* h  = (float*)d_ws;                                  // 1,048,576 f32
  float* s1 = h + (long long)BS * N_NODES * FOUT;            // 16384 f32
  float* s2 = s1 + BS * N_NODES;                             // 16384 f32
  short* hp = (short*)(s2 + BS * N_NODES);                   // 1,048,576 bf16
  unsigned int* mask32 = (unsigned int*)(hp + (long long)BS * N_NODES * FOUT); // 131072 u32

  gat_h<<<BS * N_NODES / 4, 256, 0, stream>>>(x, W, a, h, s1, s2);
  pack_mask<<<N_NODES * N_NODES / 64 / 4, 256, 0, stream>>>(adj, mask32);
  pack_h<<<BS * N_NODES * FOUT / 512 / 4, 256, 0, stream>>>(h, hp);
  gat_attn<<<dim3(N_NODES / 16, BS), 256, 0, stream>>>(mask32, hp, s1, s2, out);
}